// Round 5
// baseline (191.214 us; speedup 1.0000x reference)
//
#include <hip/hip_runtime.h>
#include <hip/hip_bf16.h>

typedef float v2f __attribute__((ext_vector_type(2)));

// ---------------- problem constants ----------------
#define B_    4
#define C_    4
#define Q_    8
#define J_    5
#define T_    15
#define NSIG  65536
#define N2SIG 32768
#define NOUT  16384
#define NCH   (B_ * C_)

// ---------------- wavelet filters (constexpr -> inline literals) ----------
constexpr float H0Oc[13] = {
    -0.00455690456024f, -0.00543947593727f,  0.01702522388155f,  0.02382538479492f,
    -0.10671180468666f,  0.01186609203379f,  0.56881042071212f,  0.75614564389252f,
     0.27529538466888f, -0.11720388769911f, -0.03887280126882f,  0.03466034684485f,
    -0.00388321199915f };
constexpr float H1Oc[13] = {
    -0.00388321199915f, -0.03466034684485f, -0.03887280126882f,  0.11720388769911f,
     0.27529538466888f, -0.75614564389252f,  0.56881042071212f, -0.01186609203379f,
    -0.10671180468666f, -0.02382538479492f,  0.01702522388155f,  0.00543947593727f,
    -0.00455690456024f };
constexpr float H0Ac[10] = {
     0.03516384f, 0.0f, -0.08832942f, 0.23389032f, 0.76027237f,
     0.58751830f, 0.0f, -0.11430184f, 0.0f, 0.0f };
constexpr float H0Bc[10] = {
     0.0f, 0.0f, -0.11430184f, 0.0f, 0.58751830f,
     0.76027237f, 0.23389032f, -0.08832942f, 0.0f, 0.03516384f };
constexpr float H1Ac[10] = {
     0.0f, 0.0f, -0.11430184f, 0.0f, 0.58751830f,
    -0.76027237f, 0.23389032f, 0.08832942f, 0.0f, -0.03516384f };
constexpr float H1Bc[10] = {
    -0.03516384f, 0.0f, 0.08832942f, 0.23389032f, -0.76027237f,
     0.58751830f, 0.0f, -0.11430184f, 0.0f, 0.0f };

// fused two-stage lowpass+decimate: out[m] = sum_n g[n] * u[4m + n - 18]
// g[n] = sum_k h[k] * h[n-2k], support 37 taps
struct Gtab { float v[37]; };
constexpr Gtab make_g() {
    Gtab g{};
    for (int n = 0; n < 37; ++n) {
        float s = 0.f;
        for (int k = 0; k < 13; ++k) {
            int l = n - 2 * k;
            if (l >= 0 && l < 13) s += H0Oc[k] * H0Oc[l];
        }
        g.v[n] = s;
    }
    return g;
}
constexpr Gtab cG = make_g();

// ---------------- tiling (M2=128, ALL 5 j's per block) --------------------
// Round-4 lesson: total VALU issue time is the floor. The per-j grid
// recomputed the lowpass chain 15x/tile where 9x suffices. This kernel
// merges all 5 j's into one block: lv0->band0->post0->lv1->band1->post1...
// Chain convs 15->9, x-load 5x->1x, grid 2048 uniform blocks.
#define M2    128                // final outputs per tile
#define MTN   (NOUT / M2)        // 128 tiles
#define MTLAST (MTN - 1)
#define NUcnt 545                // 4*(M2-1) + 37
#define NUP   552                // padded U plane stride (v2f elems)
#define NBcnt 657                // NUcnt + 112 (D=8 tap halo)
#define NBP   664
#define S_    808                // x window: [0, 804) needed, padded

// LDS carve (floats) — U planes now DEDICATED (chain planes stay live
// across posts, so no aliasing with X/L1/PP*):
//   [0,808)     X            |  [808,1616)  L1
//   PP0 = v2f @ float 0      (p in [19,784) -> floats [38,1568), X/L1 dead by then)
//   PP1 = v2f @ float 1616   (p in [10,793) -> floats [1636,3202))
//   U0  = v2f @ float 3232   |  U1 = v2f @ float 4336
//   sRI = v2f @ float 5440   -> end 6768 floats = 27072 B -> 5-6 blocks/CU
#define SMEM_FLOATS (4 * S_ + 4 * NUP + 2 * NBP)   // 6768

__device__ __forceinline__ v2f zmask(v2f a, bool ok) {
    if (!ok) { a.x = 0.f; a.y = 0.f; }
    return a;
}

// ---------------- post stage (u + fused downsample), templated on D ------
// NOTE (round-1 lesson): U-plane layout kept deliberately INTERLEAVED
// (U0[i] linear writes, up[4*mo+n] reads). The 16-way read conflict is
// hidden under VALU issue; "fixing" it in r1 regressed 25%.
// NOTE (round-3 lesson): taps[15] form needs ~48 VGPR; keep launch bound
// cap >= ~84 or it spills to scratch (WRITE_SIZE 666MB disaster).
template<int D>
__device__ __forceinline__ void post_stage(
        const v2f* __restrict__ sRI, v2f* __restrict__ U0, v2f* __restrict__ U1,
        const float* __restrict__ cw, const float* __restrict__ roots,
        float beta, int j, int b, int c, int m0, int mt, int tid,
        float* __restrict__ out) {
    const float lg_is = -0.5f * (float)j;                // log2(inv_scale)
    const float beta2 = beta * exp2f(0.5f * (float)j);   // beta * scale
    const int   u_lo  = 4 * m0 - 18;
    // downsample work split: waves 0-1 -> qp=0, waves 2-3 -> qp=1 (uniform)
    const int   qp  = tid >> 7;
    const int   mo  = tid & 127;
    const int   m   = m0 + mo;
    const bool edge = (mt == 0 && mo < 3) || (mt == MTLAST && mo >= 125);

    for (int g2 = 0; g2 < 2; ++g2) {
        // uniform weights / alphas for this group of 4 q's (wave-uniform
        // addresses -> s_loads, live in SGPRs)
        float w[4][T_], al[4], cq[4];
        #pragma unroll
        for (int qq = 0; qq < 4; ++qq) {
            const int o = c * Q_ + g2 * 4 + qq;
            #pragma unroll
            for (int t = 0; t < T_; t++) w[qq][t] = cw[(size_t)(j * 32 + o) * T_ + t];
            al[qq] = 1.f / (1.f + __expf(-roots[j * 32 + o]));
            cq[qq] = al[qq] * lg_is;
        }

        // ---- u stage: batched tap reads (r2-proven form) ----
        for (int i = tid; i < NUcnt; i += 256) {
            const int n = u_lo + i;
            const bool ok = ((unsigned)n < (unsigned)NSIG);
            const v2f* tp = sRI + (i + 56 - 7 * D);
            v2f taps[T_];
            #pragma unroll
            for (int t = 0; t < T_; t++) taps[t] = tp[t * D];
            float uq[4];
            #pragma unroll
            for (int qq = 0; qq < 4; ++qq) {
                v2f ri; ri.x = 0.f; ri.y = 0.f;
                #pragma unroll
                for (int t = 0; t < T_; t++) ri += w[qq][t] * taps[t];
                float z2 = fmaf(ri.x, ri.x, ri.y * ri.y);
                // single-instruction transcendentals (v_sqrt/v_log/v_exp)
                float us = __builtin_amdgcn_sqrtf(z2);
                float lg = __builtin_amdgcn_logf(us + beta2);
                float u  = __builtin_amdgcn_exp2f(fmaf(al[qq], lg, cq[qq]));
                uq[qq] = ok ? u : 0.f;
            }
            v2f p0; p0.x = uq[0]; p0.y = uq[1];
            v2f p1; p1.x = uq[2]; p1.y = uq[3];
            U0[i] = p0; U1[i] = p1;
        }
        __syncthreads();

        // ---- fused 37-tap stride-4 downsample, one output per thread ----
        {
            const v2f* up = qp ? U1 : U0;
            const v2f* ub = up + 4 * mo;
            v2f acc; acc.x = 0.f; acc.y = 0.f;
            #pragma unroll
            for (int n = 0; n < 37; ++n) acc += cG.v[n] * ub[n];
            if (edge) {
                // exact two-stage computation honoring v-plane masking
                v2f a2; a2.x = 0.f; a2.y = 0.f;
                for (int k = 0; k < 13; ++k) {
                    int p = 2 * m + k - 6;
                    if (p < 0 || p >= N2SIG) continue;
                    v2f v; v.x = 0.f; v.y = 0.f;
                    for (int l = 0; l < 13; ++l)
                        v += H0Oc[l] * up[4 * mo + 2 * k + l];
                    a2 += H0Oc[k] * v;
                }
                acc = a2;
            }
            const int o = c * Q_ + g2 * 4 + 2 * qp;
            out[((size_t)b * 160 + j * 32 + o)     * NOUT + m] = acc.x;
            out[((size_t)b * 160 + j * 32 + o + 1) * NOUT + m] = acc.y;
        }
        __syncthreads();   // protect U planes (and sRI for next band) 
    }
}

// ---------------- fused kernel: one block = one tile, ALL 5 j's ----------
// launch_bounds (256,6): VGPR cap ~84 — taps[15] form fits (natural ~48,
// r2-measured), no spill. LDS 27.1KB -> 5-6 blocks/CU resident.
__global__ __launch_bounds__(256, 6) void murenn_all(
        const float* __restrict__ x,
        const float* __restrict__ cw,
        const float* __restrict__ roots,
        const float* __restrict__ beta_p,
        float* __restrict__ out) {
    __shared__ __align__(16) float smem[SMEM_FLOATS];
    float* X   = smem;                        // [0,808)
    float* L1  = smem + S_;                   // [808,1616)
    v2f*   PP0 = (v2f*)smem;                  // aliases X/L1 (both dead at lv2)
    v2f*   PP1 = (v2f*)(smem + 2 * S_);       // floats [1616,3232)
    v2f*   U0  = (v2f*)(smem + 4 * S_);       // floats [3232,4336) DEDICATED
    v2f*   U1  = (v2f*)(smem + 4 * S_ + 2 * NUP);  // floats [4336,5440)
    v2f*   sRI = (v2f*)(smem + 4 * S_ + 4 * NUP);  // floats [5440,6768)

    const int tid = threadIdx.x;
    const int mt  = blockIdx.x;               // 0..127
    const int ch  = blockIdx.y;               // b*C + c
    const int b   = ch >> 2, c = ch & 3;
    const int m0  = mt * M2;
    const int ofs = 4 * m0 - 147;             // window start (bp index 0 at p=73)
    const float beta = beta_p[0];
    const float* xc = x + (size_t)ch * NSIG;

    // ---- load x window (ONCE per tile, serves all 5 j's) ----
    for (int p = tid; p < S_; p += 256) {
        int g = ofs + p;
        X[p] = ((unsigned)g < (unsigned)NSIG) ? xc[g] : 0.f;
    }
    __syncthreads();

    // ================= level 0 =================
    // band0: conv13(X, H1O) -> sRI   (reads X[67,736) c [0,808))
    for (int i = tid; i < NBcnt; i += 256) {
        int p = 73 + i, g = ofs + p;
        float a = 0.f;
        #pragma unroll
        for (int k = 0; k < 13; k++) a += H1Oc[k] * X[p + k - 6];
        if ((unsigned)g >= (unsigned)NSIG) a = 0.f;
        v2f r; r.x = a; r.y = a;
        sRI[i] = r;
    }
    __syncthreads();
    post_stage<1>(sRI, U0, U1, cw, roots, beta, 0, b, c, m0, mt, tid, out);

    // lv0: conv13(X, H0O) -> L1 on [6,798)
    for (int p = 6 + tid; p < 798; p += 256) {
        int g = ofs + p;
        float a = 0.f;
        #pragma unroll
        for (int k = 0; k < 13; k++) a += H0Oc[k] * X[p + k - 6];
        L1[p] = ((unsigned)g < (unsigned)NSIG) ? a : 0.f;
    }
    __syncthreads();

    // ================= level 1 =================
    // band1: conv10(L1, H1A/H1B) -> sRI   (reads L1[69,735) c [6,798))
    for (int i = tid; i < NBcnt; i += 256) {
        int p = 73 + i, g = ofs + p;
        v2f r; r.x = 0.f; r.y = 0.f;
        #pragma unroll
        for (int k = 0; k < 10; k++) {
            v2f hk; hk.x = H1Ac[k]; hk.y = H1Bc[k];
            r += hk * L1[p + k - 4];
        }
        sRI[i] = zmask(r, (unsigned)g < (unsigned)NSIG);
    }
    __syncthreads();
    post_stage<1>(sRI, U0, U1, cw, roots, beta, 1, b, c, m0, mt, tid, out);

    // lv1 (d=1, pad 4): (la2,lb2) -> PP1 on [10,793)
    for (int p = 10 + tid; p < 793; p += 256) {
        int g = ofs + p;
        v2f a; a.x = 0.f; a.y = 0.f;
        #pragma unroll
        for (int k = 0; k < 10; k++) {
            v2f hk; hk.x = H0Ac[k]; hk.y = H0Bc[k];
            a += hk * L1[p + k - 4];
        }
        PP1[p] = zmask(a, (unsigned)g < (unsigned)NSIG);
    }
    __syncthreads();

    // ================= level 2 =================
    // band2: (PP1, 2k-9) -> sRI   (reads PP1[64,739) c [10,793))
    for (int i = tid; i < NBcnt; i += 256) {
        int p = 73 + i, g = ofs + p;
        v2f r; r.x = 0.f; r.y = 0.f;
        #pragma unroll
        for (int k = 0; k < 10; k++) {
            v2f hk; hk.x = H1Ac[k]; hk.y = H1Bc[k];
            r += hk * PP1[p + 2 * k - 9];
        }
        sRI[i] = zmask(r, (unsigned)g < (unsigned)NSIG);
    }
    __syncthreads();
    post_stage<2>(sRI, U0, U1, cw, roots, beta, 2, b, c, m0, mt, tid, out);

    // lv2 (d=2, pad 9): (la3,lb3) -> PP0 on [19,784)
    // PP0 spans floats [38,1568): X and L1 are BOTH dead here (lv1/band1 done)
    for (int p = 19 + tid; p < 784; p += 256) {
        int g = ofs + p;
        v2f a; a.x = 0.f; a.y = 0.f;
        #pragma unroll
        for (int k = 0; k < 10; k++) {
            v2f hk; hk.x = H0Ac[k]; hk.y = H0Bc[k];
            a += hk * PP1[p + 2 * k - 9];
        }
        PP0[p] = zmask(a, (unsigned)g < (unsigned)NSIG);
    }
    __syncthreads();

    // ================= level 3 =================
    // band3: (PP0, 4k-18) -> sRI   (reads PP0[55,748) c [19,784))
    for (int i = tid; i < NBcnt; i += 256) {
        int p = 73 + i, g = ofs + p;
        v2f r; r.x = 0.f; r.y = 0.f;
        #pragma unroll
        for (int k = 0; k < 10; k++) {
            v2f hk; hk.x = H1Ac[k]; hk.y = H1Bc[k];
            r += hk * PP0[p + 4 * k - 18];
        }
        sRI[i] = zmask(r, (unsigned)g < (unsigned)NSIG);
    }
    __syncthreads();
    post_stage<4>(sRI, U0, U1, cw, roots, beta, 3, b, c, m0, mt, tid, out);

    // lv3 (d=4, pad 18): (la4,lb4) -> PP1 on [37,766)  (old PP1 dead)
    for (int p = 37 + tid; p < 766; p += 256) {
        int g = ofs + p;
        v2f a; a.x = 0.f; a.y = 0.f;
        #pragma unroll
        for (int k = 0; k < 10; k++) {
            v2f hk; hk.x = H0Ac[k]; hk.y = H0Bc[k];
            a += hk * PP0[p + 4 * k - 18];
        }
        PP1[p] = zmask(a, (unsigned)g < (unsigned)NSIG);
    }
    __syncthreads();

    // ================= level 4 =================
    // band4: (PP1, 8k-36) -> sRI   (reads PP1[37,766) exactly)
    for (int i = tid; i < NBcnt; i += 256) {
        int p = 73 + i, g = ofs + p;
        v2f r; r.x = 0.f; r.y = 0.f;
        #pragma unroll
        for (int k = 0; k < 10; k++) {
            v2f hk; hk.x = H1Ac[k]; hk.y = H1Bc[k];
            r += hk * PP1[p + 8 * k - 36];
        }
        sRI[i] = zmask(r, (unsigned)g < (unsigned)NSIG);
    }
    __syncthreads();
    post_stage<8>(sRI, U0, U1, cw, roots, beta, 4, b, c, m0, mt, tid, out);
}

// ---------------- launch ----------------
extern "C" void kernel_launch(void* const* d_in, const int* in_sizes, int n_in,
                              void* d_out, int out_size, void* d_ws, size_t ws_size,
                              hipStream_t stream) {
    (void)in_sizes; (void)n_in; (void)out_size; (void)d_ws; (void)ws_size;
    const float* x     = (const float*)d_in[0];
    const float* cw    = (const float*)d_in[1];
    const float* roots = (const float*)d_in[2];
    const float* beta  = (const float*)d_in[3];
    float* out = (float*)d_out;

    dim3 grid(MTN, NCH);                 // (128, 16) — uniform work per block
    murenn_all<<<grid, 256, 0, stream>>>(x, cw, roots, beta, out);
}